// Round 11
// baseline (590.688 us; speedup 1.0000x reference)
//
#include <hip/hip_runtime.h>
#include <hip/hip_cooperative_groups.h>
#include <math.h>

namespace cg = cooperative_groups;

constexpr int N = 50000;   // nodes
constexpr int E = 800000;  // edges (without self-loops)
constexpr int F = 128;     // features / hidden
constexpr int G = 256;     // graphs
constexpr int T = 4;       // tasks

constexpr int BSH   = 5;                         // 32 nodes per bucket
constexpr int BNODES= 1 << BSH;
constexpr int NBUCK = (N + BNODES - 1) / BNODES; // 1563
constexpr int CHUNK = 4096;                      // edges per partition unit (196 units)
constexpr int NCHUNK= (E + CHUNK - 1) / CHUNK;   // 196
constexpr int SSH   = 13;                        // src-slice shift: 8192-node slices

constexpr int GB1 = (N + 63) / 64;               // 782 gemm tiles
constexpr int GFB = GB1 + NCHUNK;                // fused gemm+fillb grid (978)
constexpr int AGB = N / 16;                      // 3125 agg blocks (16 nodes/block)

// merged-kernel phase-1 unit layout: [wcastW1 64 | wcastW2 64 | zero pooled 128 | hist 196]
constexpr int MP_W2  = 64;
constexpr int MP_Z0  = 128;
constexpr int MP_H0  = 256;
constexpr int MP_END = MP_H0 + NCHUNK;           // 452
constexpr int MGRID  = 512;                      // 2 blocks/CU — generous co-residency margin

// k_pre (fallback) block-range layout
constexpr int PRE_BLKS = MP_END;                 // 452

typedef __attribute__((ext_vector_type(8))) short short8;
typedef __attribute__((ext_vector_type(4))) float floatx4;

// bf16 <-> fp32 helpers (RNE on pack; values are finite)
__device__ inline float bf2f(unsigned short u) {
    union { unsigned int i; float f; } v;
    v.i = ((unsigned int)u) << 16;
    return v.f;
}
__device__ inline unsigned short f2bf(float f) {
    union { float f; unsigned int i; } v;
    v.f = f;
    unsigned int r = v.i + 0x7FFF + ((v.i >> 16) & 1);
    return (unsigned short)(r >> 16);
}
__device__ inline unsigned int pack2bf(float a, float b) {
    return (unsigned int)f2bf(a) | ((unsigned int)f2bf(b) << 16);
}

// pack W (fp32) -> MFMA-B-fragment order, hi/lo bf16 split
__device__ inline void wcast_one(const float* __restrict__ W,
                                 unsigned short* __restrict__ Whi,
                                 unsigned short* __restrict__ Wlo, int i) {
    if (i >= F * F) return;
    int k = i >> 7, n = i & 127;
    float w = W[i];
    unsigned short hi = f2bf(w);
    unsigned short lo = f2bf(w - bf2f(hi));
    int s = k >> 5, q = (k >> 3) & 3, j = k & 7;
    int idx = (((s * 128 + n) * 4 + q) * 8) + j;
    Whi[idx] = hi;
    Wlo[idx] = lo;
}

// ---------------- GEMM tile body (direct-reg A, no LDS): shared by coop + fallback ----------
__device__ __forceinline__ void gemm_tile(const float* __restrict__ x,
                                          const unsigned short* __restrict__ w1h,
                                          const unsigned short* __restrict__ w1l,
                                          unsigned short* __restrict__ tmp16,
                                          int tile, int t) {
    int wv = t >> 6;
    int lane = t & 63;
    int c16 = lane & 15;
    int q = lane >> 4;
    int arow = tile * 64 + wv * 16 + c16;

    short8 afr[4];
    if (arow < N) {
        const float4* xr = (const float4*)(x + (size_t)arow * 128);
#pragma unroll
        for (int s = 0; s < 4; ++s) {
            float4 v0 = xr[s * 8 + q * 2];
            float4 v1 = xr[s * 8 + q * 2 + 1];
            short8 a;
            a[0] = (short)f2bf(v0.x); a[1] = (short)f2bf(v0.y);
            a[2] = (short)f2bf(v0.z); a[3] = (short)f2bf(v0.w);
            a[4] = (short)f2bf(v1.x); a[5] = (short)f2bf(v1.y);
            a[6] = (short)f2bf(v1.z); a[7] = (short)f2bf(v1.w);
            afr[s] = a;
        }
    } else {
#pragma unroll
        for (int s = 0; s < 4; ++s) afr[s] = (short8){0,0,0,0,0,0,0,0};
    }

    floatx4 acc[8];
#pragma unroll
    for (int nt = 0; nt < 8; ++nt) acc[nt] = (floatx4){0.f, 0.f, 0.f, 0.f};

    const short8* WH = (const short8*)w1h;
    const short8* WL = (const short8*)w1l;
#pragma unroll
    for (int s = 0; s < 4; ++s) {
        int wb = s * 512 + c16 * 4 + q;
#pragma unroll
        for (int nt = 0; nt < 8; ++nt) {
            acc[nt] = __builtin_amdgcn_mfma_f32_16x16x32_bf16(afr[s], WH[wb + nt * 64], acc[nt], 0, 0, 0);
            acc[nt] = __builtin_amdgcn_mfma_f32_16x16x32_bf16(afr[s], WL[wb + nt * 64], acc[nt], 0, 0, 0);
        }
    }

    int rbase = tile * 64 + wv * 16 + q * 4;
#pragma unroll
    for (int r = 0; r < 4; ++r) {
        int row = rbase + r;
        if (row < N) {
#pragma unroll
            for (int nt = 0; nt < 8; ++nt)
                tmp16[row * 128 + nt * 16 + c16] = f2bf(acc[nt][r]);
        }
    }
}

// ---------------- fillb body (smem laid out by caller): shared by coop + fallback ----------
__device__ __forceinline__ void fillb_body(char* smem, int chunk, int t,
                                           const int* __restrict__ src,
                                           const int* __restrict__ dst,
                                           const int* __restrict__ cnts,
                                           const int* __restrict__ btot,
                                           int* __restrict__ bucketbase,
                                           unsigned int* __restrict__ staging) {
    int* bb   = (int*)smem;                    // NBUCK+1 = 1564 (6256 B)
    int* part = (int*)(smem + 6256);           // 256 (1024 B)
    int* lofs = (int*)(smem + 7280);           // NBUCK (6252 B) -> 13532 total

    constexpr int CH = (NBUCK + 255) / 256;    // 7
    int beg = t * CH;
    int end = (beg + CH < NBUCK) ? beg + CH : NBUCK;
    int tot[CH];
    int s = 0;
    for (int i = beg; i < end; ++i) {
        tot[i - beg] = btot[i];
        s += btot[i];
    }
    part[t] = s;
    __syncthreads();
    for (int off = 1; off < 256; off <<= 1) {
        int u = (t >= off) ? part[t - off] : 0;
        __syncthreads();
        part[t] += u;
        __syncthreads();
    }
    int run = (t == 0) ? 0 : part[t - 1];
    for (int i = beg; i < end; ++i) {
        bb[i] = run;
        run += tot[i - beg];
    }
    if (t == 255) bb[NBUCK] = part[255];       // == E
    __syncthreads();
    if (chunk == 0)
        for (int i = t; i <= NBUCK; i += 256) bucketbase[i] = bb[i];

    for (int i = t; i < NBUCK; i += 256)
        lofs[i] = bb[i] + cnts[chunk * NBUCK + i];
    __syncthreads();

    int base = chunk * CHUNK;
    for (int i = t; i < CHUNK; i += 256) {
        int e = base + i;
        if (e < E) {
            int d = dst[e];
            int pos = atomicAdd(&lofs[d >> BSH], 1);   // LDS atomic
            staging[pos] = (unsigned int)src[e] | ((unsigned int)(d & (BNODES - 1)) << 16);
        }
    }
}

// ---------------- passB body (smem laid out by caller): shared by coop + fallback ----------
__device__ __forceinline__ void passB_body(char* smem, int bk, int t,
                                           const unsigned int* __restrict__ staging,
                                           const int* __restrict__ bucketbase,
                                           int* __restrict__ csr,
                                           int* __restrict__ rowstart,
                                           float* __restrict__ dinv,
                                           unsigned short* __restrict__ tmp16) {
    unsigned int* ent = (unsigned int*)smem;         // 4096 B
    int* hh       = (int*)(smem + 4096);             // 1024 B (BNODES*8)
    int* off_a    = (int*)(smem + 5120);             // 1024 B
    int* nodebase = (int*)(smem + 6144);             // 128 B
    int* ndeg     = (int*)(smem + 6272);             // 128 B
    float* sdinv  = (float*)(smem + 6400);           // 128 B

    int jb = bucketbase[bk], je = bucketbase[bk + 1];
    int M = je - jb;
    if (M > 1024) M = 1024;
    if (t < BNODES * 8) hh[t] = 0;
    __syncthreads();

    for (int i = t; i < M; i += 256) {
        unsigned int en = staging[jb + i];
        ent[i] = en;
        int key = (((en >> 16) & (BNODES - 1)) << 3) | ((en & 0xFFFFu) >> SSH);
        atomicAdd(&hh[key], 1);
    }
    __syncthreads();

    if (t < BNODES) {
        int s = 0;
#pragma unroll
        for (int c = 0; c < 8; ++c) s += hh[t * 8 + c];
        ndeg[t] = s;
    }
    __syncthreads();
    if (t == 0) {
        int run = jb;
        for (int k = 0; k < BNODES; ++k) {
            nodebase[k] = run;
            run += ndeg[k];
        }
    }
    __syncthreads();
    if (t < BNODES) {
        int run = nodebase[t];
#pragma unroll
        for (int c = 0; c < 8; ++c) {
            off_a[t * 8 + c] = run;
            run += hh[t * 8 + c];
        }
        float dv = rsqrtf((float)(ndeg[t] + 1));     // +1 self-loop
        sdinv[t] = dv;
        int node = bk * BNODES + t;
        if (node < N) {
            rowstart[node] = nodebase[t];
            dinv[node] = dv;
        }
    }
    if (bk == 0 && t == 0) rowstart[N] = E;
    __syncthreads();

    for (int i = t; i < M; i += 256) {
        unsigned int en = ent[i];
        int key = (((en >> 16) & (BNODES - 1)) << 3) | ((en & 0xFFFFu) >> SSH);
        int loc = atomicAdd(&off_a[key], 1);
        csr[loc] = (int)(en & 0xFFFFu);
    }

    // in-place scale: tmp16[row] *= dinv[row] for this bucket's 32 rows
    uint4* t4 = (uint4*)tmp16;
    for (int i = t; i < BNODES * 16; i += 256) {     // 512 uint4, 2 per thread
        int rl = i >> 4, qi = i & 15;
        int node = bk * BNODES + rl;
        if (node < N) {
            float dv = sdinv[rl];
            uint4 u = t4[node * 16 + qi];
            uint4 o;
            o.x = pack2bf(bf2f((unsigned short)(u.x & 0xFFFFu)) * dv, bf2f((unsigned short)(u.x >> 16)) * dv);
            o.y = pack2bf(bf2f((unsigned short)(u.y & 0xFFFFu)) * dv, bf2f((unsigned short)(u.y >> 16)) * dv);
            o.z = pack2bf(bf2f((unsigned short)(u.z & 0xFFFFu)) * dv, bf2f((unsigned short)(u.z >> 16)) * dv);
            o.w = pack2bf(bf2f((unsigned short)(u.w & 0xFFFFu)) * dv, bf2f((unsigned short)(u.w >> 16)) * dv);
            t4[node * 16 + qi] = o;
        }
    }
}

// ================= merged preprocessing (cooperative, 4 grid-stride phases) =================
__global__ __launch_bounds__(256) void k_merged(
        const float* __restrict__ x, const float* __restrict__ W1, const float* __restrict__ W2,
        unsigned short* __restrict__ w1h, unsigned short* __restrict__ w1l,
        unsigned short* __restrict__ w2h, unsigned short* __restrict__ w2l,
        const int* __restrict__ src, const int* __restrict__ dst,
        int* __restrict__ cnts, int* __restrict__ btot, int* __restrict__ bucketbase,
        unsigned int* __restrict__ staging, int* __restrict__ csr, int* __restrict__ rowstart,
        float* __restrict__ dinv, unsigned short* __restrict__ tmp16,
        float* __restrict__ pooled) {
    cg::grid_group grid = cg::this_grid();
    __shared__ __align__(16) char smem[13536];
    int b = blockIdx.x, t = threadIdx.x;

    // ---- P1: wcast W1/W2 + zero pooled + per-chunk bucket histogram (grid-stride) ----
    for (int u = b; u < MP_END; u += MGRID) {
        __syncthreads();
        if (u < MP_W2) {
            wcast_one(W1, w1h, w1l, u * 256 + t);
        } else if (u < MP_Z0) {
            wcast_one(W2, w2h, w2l, (u - MP_W2) * 256 + t);
        } else if (u < MP_H0) {
            pooled[(u - MP_Z0) * 256 + t] = 0.f;       // G*F = 32768 exactly
        } else {
            int chunk = u - MP_H0;
            int* h = (int*)smem;
            for (int i = t; i < NBUCK; i += 256) h[i] = 0;
            __syncthreads();
            int base = chunk * CHUNK;
            for (int i = t; i < CHUNK; i += 256) {
                int e = base + i;
                if (e < E) atomicAdd(&h[dst[e] >> BSH], 1);   // LDS atomic
            }
            __syncthreads();
            for (int i = t; i < NBUCK; i += 256) cnts[chunk * NBUCK + i] = h[i];
        }
    }
    __threadfence();
    grid.sync();

    // ---- P2: colscan (grid-stride) ----
    for (int j = b; j < NBUCK; j += MGRID) {
        __syncthreads();
        int* part = (int*)smem;
        int k0 = 2 * t, k1 = 2 * t + 1;
        int v0 = (k0 < NCHUNK) ? cnts[k0 * NBUCK + j] : 0;
        int v1 = (k1 < NCHUNK) ? cnts[k1 * NBUCK + j] : 0;
        int s = v0 + v1;
        part[t] = s;
        __syncthreads();
        for (int off = 1; off < 256; off <<= 1) {
            int u = (t >= off) ? part[t - off] : 0;
            __syncthreads();
            part[t] += u;
            __syncthreads();
        }
        int excl = part[t] - s;
        if (k0 < NCHUNK) cnts[k0 * NBUCK + j] = excl;
        if (k1 < NCHUNK) cnts[k1 * NBUCK + j] = excl + v0;
        if (t == 255) btot[j] = part[255];
    }
    __threadfence();
    grid.sync();

    // ---- P3: layer-1 GEMM (direct-reg) + fillb partition (grid-stride) ----
    for (int u = b; u < GFB; u += MGRID) {
        __syncthreads();
        if (u < GB1) {
            gemm_tile(x, w1h, w1l, tmp16, u, t);
        } else {
            fillb_body(smem, u - GB1, t, src, dst, cnts, btot, bucketbase, staging);
        }
    }
    __threadfence();
    grid.sync();

    // ---- P4: passB counting sort + dinv + tmp16 pre-scale (grid-stride) ----
    for (int bk = b; bk < NBUCK; bk += MGRID) {
        __syncthreads();
        passB_body(smem, bk, t, staging, bucketbase, csr, rowstart, dinv, tmp16);
    }
}

// ================= fallback chain (r9-proven separate kernels) =================
__global__ __launch_bounds__(256) void k_pre(const float* __restrict__ W1, const float* __restrict__ W2,
                                             unsigned short* __restrict__ w1h, unsigned short* __restrict__ w1l,
                                             unsigned short* __restrict__ w2h, unsigned short* __restrict__ w2l,
                                             const int* __restrict__ dst, int* __restrict__ cnts,
                                             float* __restrict__ pooled) {
    __shared__ int h[NBUCK];
    int b = blockIdx.x, t = threadIdx.x;
    if (b < MP_W2) {
        wcast_one(W1, w1h, w1l, b * 256 + t);
    } else if (b < MP_Z0) {
        wcast_one(W2, w2h, w2l, (b - MP_W2) * 256 + t);
    } else if (b < MP_H0) {
        pooled[(b - MP_Z0) * 256 + t] = 0.f;
    } else {
        int chunk = b - MP_H0;
        for (int i = t; i < NBUCK; i += 256) h[i] = 0;
        __syncthreads();
        int base = chunk * CHUNK;
        for (int i = t; i < CHUNK; i += 256) {
            int e = base + i;
            if (e < E) atomicAdd(&h[dst[e] >> BSH], 1);
        }
        __syncthreads();
        for (int i = t; i < NBUCK; i += 256) cnts[chunk * NBUCK + i] = h[i];
    }
}

__global__ __launch_bounds__(256) void k_colscan(int* __restrict__ cnts, int* __restrict__ btot) {
    __shared__ int part[256];
    int j = blockIdx.x, t = threadIdx.x;
    int k0 = 2 * t, k1 = 2 * t + 1;
    int v0 = (k0 < NCHUNK) ? cnts[k0 * NBUCK + j] : 0;
    int v1 = (k1 < NCHUNK) ? cnts[k1 * NBUCK + j] : 0;
    int s = v0 + v1;
    part[t] = s;
    __syncthreads();
    for (int off = 1; off < 256; off <<= 1) {
        int u = (t >= off) ? part[t - off] : 0;
        __syncthreads();
        part[t] += u;
        __syncthreads();
    }
    int excl = part[t] - s;
    if (k0 < NCHUNK) cnts[k0 * NBUCK + j] = excl;
    if (k1 < NCHUNK) cnts[k1 * NBUCK + j] = excl + v0;
    if (t == 255) btot[j] = part[255];
}

__global__ __launch_bounds__(256) void k_gemmfill(const float* __restrict__ x,
                                                  const unsigned short* __restrict__ w1h,
                                                  const unsigned short* __restrict__ w1l,
                                                  unsigned short* __restrict__ tmp16,
                                                  const int* __restrict__ src,
                                                  const int* __restrict__ dst,
                                                  const int* __restrict__ cnts,
                                                  const int* __restrict__ btot,
                                                  int* __restrict__ bucketbase,
                                                  unsigned int* __restrict__ staging) {
    __shared__ __align__(16) char smem[13536];
    int b = blockIdx.x, t = threadIdx.x;
    if (b < GB1) {
        gemm_tile(x, w1h, w1l, tmp16, b, t);
        return;
    }
    fillb_body(smem, b - GB1, t, src, dst, cnts, btot, bucketbase, staging);
}

__global__ __launch_bounds__(256) void k_passB(const unsigned int* __restrict__ staging,
                                               const int* __restrict__ bucketbase,
                                               int* __restrict__ csr,
                                               int* __restrict__ rowstart,
                                               float* __restrict__ dinv,
                                               unsigned short* __restrict__ tmp16) {
    __shared__ __align__(16) char smem[13536];
    passB_body(smem, blockIdx.x, threadIdx.x, staging, bucketbase, csr, rowstart, dinv, tmp16);
}

// 8 bf16 (uint4) add into 8 fp32 accumulators (coefficient-free hot path)
__device__ inline void add8(const uint4& u, float* acc) {
    union { unsigned int i; float f; } a;
    a.i = u.x << 16;          acc[0] += a.f;
    a.i = u.x & 0xFFFF0000u;  acc[1] += a.f;
    a.i = u.y << 16;          acc[2] += a.f;
    a.i = u.y & 0xFFFF0000u;  acc[3] += a.f;
    a.i = u.z << 16;          acc[4] += a.f;
    a.i = u.z & 0xFFFF0000u;  acc[5] += a.f;
    a.i = u.w << 16;          acc[6] += a.f;
    a.i = u.w & 0xFFFF0000u;  acc[7] += a.f;
}

// 8 bf16 (uint4) fma into 8 fp32 accumulators (masked tail + pooling)
__device__ inline void fma8(const uint4& u, float c, float* acc) {
    union { unsigned int i; float f; } a;
    a.i = u.x << 16;          acc[0] = fmaf(a.f, c, acc[0]);
    a.i = u.x & 0xFFFF0000u;  acc[1] = fmaf(a.f, c, acc[1]);
    a.i = u.y << 16;          acc[2] = fmaf(a.f, c, acc[2]);
    a.i = u.y & 0xFFFF0000u;  acc[3] = fmaf(a.f, c, acc[3]);
    a.i = u.z << 16;          acc[4] = fmaf(a.f, c, acc[4]);
    a.i = u.z & 0xFFFF0000u;  acc[5] = fmaf(a.f, c, acc[5]);
    a.i = u.w << 16;          acc[6] = fmaf(a.f, c, acc[6]);
    a.i = u.w & 0xFFFF0000u;  acc[7] = fmaf(a.f, c, acc[7]);
}

// agg inner loop (round-5 proven form): 8-deep full chunks with next-chunk csr
// prefetch; one masked tail. r6 (16-deep ILP) and r7 (node-split TLP) both
// regressed — the gather is at the memory-system's random-access service limit.
__device__ __forceinline__ void agg_loop(const uint4* __restrict__ t8l,  // t8 + lane
                                         const int* __restrict__ csr,
                                         int jb, int je, float* acc) {
    int n8 = (je - jb) >> 3;
    int j = jb;
    if (n8 > 0) {
        int e[8];
#pragma unroll
        for (int k = 0; k < 8; ++k) e[k] = csr[j + k];
        for (int c = 0; c < n8; ++c) {
            uint4 u[8];
#pragma unroll
            for (int k = 0; k < 8; ++k) u[k] = t8l[e[k] * 16];
            j += 8;
            if (c + 1 < n8) {
#pragma unroll
                for (int k = 0; k < 8; ++k) e[k] = csr[j + k];   // prefetch next chunk's indices
            }
#pragma unroll
            for (int k = 0; k < 8; ++k) add8(u[k], acc);
        }
    }
    if (j < je) {                       // masked tail (1..7 edges)
        int e[8];
        float msk[8];
#pragma unroll
        for (int k = 0; k < 8; ++k) {
            int idx = j + k;
            e[k] = csr[idx < je ? idx : je - 1];
            msk[k] = (idx < je) ? 1.0f : 0.0f;
        }
        uint4 u[8];
#pragma unroll
        for (int k = 0; k < 8; ++k) u[k] = t8l[e[k] * 16];
#pragma unroll
        for (int k = 0; k < 8; ++k) fma8(u[k], msk[k], acc);
    }
}

// ---------------- fused layer-1 agg + layer-2 GEMM (16 nodes/block) ----------------
__global__ __launch_bounds__(256) void k_agg1gemm(const unsigned short* __restrict__ tmp16,
                                                  const int* __restrict__ csr,
                                                  const int* __restrict__ rowstart,
                                                  const float* __restrict__ dinv,
                                                  const float* __restrict__ bias,
                                                  const unsigned short* __restrict__ w2h,
                                                  const unsigned short* __restrict__ w2l,
                                                  unsigned short* __restrict__ tmp2) {
    __shared__ __align__(16) unsigned short Albs[16 * 136];
    int tid = threadIdx.x;
    int row0 = blockIdx.x * 16;

    // ---- phase A: aggregation (h1 = relu(dinv_d * sum(tmp16[s]) + b1); tmp16 pre-scaled) ----
    {
        int node = row0 + (tid >> 4);
        int lane = tid & 15;
        const uint4* t8l = (const uint4*)tmp16 + lane;
        float acc[8] = {0.f, 0.f, 0.f, 0.f, 0.f, 0.f, 0.f, 0.f};
        add8(t8l[node * 16], acc);                       // self-loop term
        agg_loop(t8l, csr, rowstart[node], rowstart[node + 1], acc);

        float di = dinv[node];
        const float4* b4 = (const float4*)bias;
        float4 ba = b4[lane * 2], bb = b4[lane * 2 + 1];
        uint4 o;
        o.x = pack2bf(fmaxf(fmaf(acc[0], di, ba.x), 0.f), fmaxf(fmaf(acc[1], di, ba.y), 0.f));
        o.y = pack2bf(fmaxf(fmaf(acc[2], di, ba.z), 0.f), fmaxf(fmaf(acc[3], di, ba.w), 0.f));
        o.z = pack2bf(fmaxf(fmaf(acc[4], di, bb.x), 0.f), fmaxf(fmaf(acc[5], di, bb.y), 0.f));
        o.w = pack2bf(fmaxf(fmaf(acc[6], di, bb.z), 0.f), fmaxf(fmaf(acc[7], di, bb.w), 0.f));
        *(uint4*)&Albs[(tid >> 4) * 136 + lane * 8] = o;
    }
    __syncthreads();

    // ---- phase B: 16-row MFMA gemm, 4 waves x 2 n-tiles; output pre-scaled by dinv ----
    int wv = tid >> 6;
    int lane = tid & 63;
    int c16 = lane & 15;
    int q = lane >> 4;

    floatx4 acc[2];
    acc[0] = (floatx4){0.f, 0.f, 0.f, 0.f};
    acc[1] = (floatx4){0.f, 0.f, 0.f, 0.f};

    const short8* WH = (const short8*)w2h;
    const short8* WL = (const short8*)w2l;
#pragma unroll
    for (int s = 0; s < 4; ++s) {
        short8 a = *(const short8*)&Albs[c16 * 136 + s * 32 + q * 8];
        int wb = s * 512 + c16 * 4 + q;
#pragma unroll
        for (int i = 0; i < 2; ++i) {
            int nt = wv * 2 + i;
            acc[i] = __builtin_amdgcn_mfma_f32_16x16x32_bf16(a, WH[wb + nt * 64], acc[i], 0, 0, 0);
            acc[i] = __builtin_amdgcn_mfma_f32_16x16x32_bf16(a, WL[wb + nt * 64], acc[i], 0, 0, 0);
        }
    }

    int rbase = row0 + q * 4;
#pragma unroll
    for (int r = 0; r < 4; ++r) {
        int row = rbase + r;
        float dv = dinv[row];
#pragma unroll
        for (int i = 0; i < 2; ++i) {
            int nt = wv * 2 + i;
            tmp2[row * 128 + nt * 16 + c16] = f2bf(acc[i][r] * dv);
        }
    }
}

// ------- layer-2 aggregation + fused pooling (batch sorted -> LDS run-reduce + atomics) -------
__global__ __launch_bounds__(256) void k_agg(const unsigned short* __restrict__ tmp16,
                                             const int* __restrict__ csr,
                                             const int* __restrict__ rowstart,
                                             const float* __restrict__ dinv,
                                             const float* __restrict__ bias,
                                             const int* __restrict__ batch,
                                             float* __restrict__ pooled) {
    __shared__ float red[16][128];
    __shared__ int gid[16];
    int tid = threadIdx.x;
    int node0 = blockIdx.x * 16;              // AGB*16 == N exactly
    int ns = tid >> 4, lane = tid & 15;
    int node = node0 + ns;
    const uint4* t8l = (const uint4*)tmp16 + lane;
    float acc[8] = {0.f, 0.f, 0.f, 0.f, 0.f, 0.f, 0.f, 0.f};
    add8(t8l[node * 16], acc);
    agg_loop(t8l, csr, rowstart[node], rowstart[node + 1], acc);

    float di = dinv[node];
    const float4* b4 = (const float4*)bias;
    float4 ba = b4[lane * 2], bb = b4[lane * 2 + 1];
    red[ns][lane * 8 + 0] = fmaxf(fmaf(acc[0], di, ba.x), 0.f);
    red[ns][lane * 8 + 1] = fmaxf(fmaf(acc[1], di, ba.y), 0.f);
    red[ns][lane * 8 + 2] = fmaxf(fmaf(acc[2], di, ba.z), 0.f);
    red[ns][lane * 8 + 3] = fmaxf(fmaf(acc[3], di, ba.w), 0.f);
    red[ns][lane * 8 + 4] = fmaxf(fmaf(acc[4], di, bb.x), 0.f);
    red[ns][lane * 8 + 5] = fmaxf(fmaf(acc[5], di, bb.y), 0.f);
    red[ns][lane * 8 + 6] = fmaxf(fmaf(acc[6], di, bb.z), 0.f);
    red[ns][lane * 8 + 7] = fmaxf(fmaf(acc[7], di, bb.w), 0.f);
    if (tid < 16) gid[tid] = batch[node0 + tid];
    __syncthreads();

    if (tid < 128) {
        int f = tid;
        float run = 0.f;
        int g = gid[0];
        for (int r = 0; r < 16; ++r) {
            if (gid[r] != g) {
                atomicAdd(&pooled[g * 128 + f], run);
                run = 0.f;
                g = gid[r];
            }
            run += red[r][f];
        }
        atomicAdd(&pooled[g * 128 + f], run);
    }
}

// ---------------- slim pool-finish + fc + head: reads pooled sums only ----------------
__global__ __launch_bounds__(128) void k_poolhead(const float* __restrict__ pooled,
                                                  const int* __restrict__ batch,
                                                  const float* __restrict__ Wfc,
                                                  const float* __restrict__ bfc,
                                                  const float* __restrict__ Wh,
                                                  const float* __restrict__ bh,
                                                  float* __restrict__ out) {
    __shared__ float p[128];
    __shared__ float zs[128];
    int g = blockIdx.x, t = threadIdx.x;

    int lo = 0, hi = N;                       // lower_bound(g)
    while (lo < hi) { int m = (lo + hi) >> 1; if (batch[m] < g) lo = m + 1; else hi = m; }
    int lo1 = lo, hi1 = N;                    // lower_bound(g+1)
    while (lo1 < hi1) { int m = (lo1 + hi1) >> 1; if (batch[m] < g + 1) lo1 = m + 1; else hi1 = m; }
    int cnt = lo1 - lo;
    float inv = 1.0f / (float)((cnt > 1) ? cnt : 1);

    p[t] = pooled[g * 128 + t] * inv;
    __syncthreads();

    float a = bfc[t];
    for (int k = 0; k < F; ++k) a = fmaf(p[k], Wfc[k * F + t], a);
    zs[t] = fmaxf(a, 0.f);
    __syncthreads();

    if (t < T * 2) {
        int task = t >> 1, c = t & 1;
        float a2 = bh[task * 2 + c];
        const float* wr = &Wh[task * F * 2 + c];
        for (int h = 0; h < F; ++h) a2 = fmaf(zs[h], wr[h * 2], a2);
        out[task * (G * 2) + g * 2 + c] = a2;
    }
}

extern "C" void kernel_launch(void* const* d_in, const int* in_sizes, int n_in,
                              void* d_out, int out_size, void* d_ws, size_t ws_size,
                              hipStream_t stream) {
    const float* x    = (const float*)d_in[0];
    const int*   ei   = (const int*)d_in[1];      // [2,E]: row0=src, row1=dst
    const int*   batch= (const int*)d_in[2];
    const float* W1   = (const float*)d_in[3];
    const float* b1   = (const float*)d_in[4];
    const float* W2   = (const float*)d_in[5];
    const float* b2   = (const float*)d_in[6];
    const float* Wfc  = (const float*)d_in[7];
    const float* bfc  = (const float*)d_in[8];
    const float* Wh   = (const float*)d_in[9];
    const float* bh   = (const float*)d_in[10];
    float* out = (float*)d_out;

    const int* srcp = ei;
    const int* dstp = ei + E;

    char* w = (char*)d_ws;
    auto alloc = [&](size_t bytes) {
        char* p = w;
        w += (bytes + 255) & ~(size_t)255;
        return p;
    };
    unsigned short* tmp16 = (unsigned short*)alloc((size_t)N * F * 2);
    unsigned short* tmp2  = (unsigned short*)alloc((size_t)N * F * 2);
    int*   csr      = (int*)  alloc((size_t)E * 4);
    unsigned int* staging = (unsigned int*)alloc((size_t)E * 4);
    int*   cnts     = (int*)  alloc((size_t)NCHUNK * NBUCK * 4);
    int*   btot     = (int*)  alloc((size_t)NBUCK * 4);
    int*   bucketbase=(int*)  alloc((size_t)(NBUCK + 1) * 4);
    int*   rowstart = (int*)  alloc((size_t)(N + 1) * 4);
    float* dinv     = (float*)alloc((size_t)N * 4);
    float* pooled   = (float*)alloc((size_t)G * F * 4);
    unsigned short* w1h = (unsigned short*)alloc((size_t)F * F * 2);
    unsigned short* w1l = (unsigned short*)alloc((size_t)F * F * 2);
    unsigned short* w2h = (unsigned short*)alloc((size_t)F * F * 2);
    unsigned short* w2l = (unsigned short*)alloc((size_t)F * F * 2);

    // merged preprocessing (1 cooperative launch); fall back to the proven 4-kernel
    // chain if the cooperative launch is rejected (capacity / capture unsupported).
    void* kargs[] = { (void*)&x, (void*)&W1, (void*)&W2,
                      (void*)&w1h, (void*)&w1l, (void*)&w2h, (void*)&w2l,
                      (void*)&srcp, (void*)&dstp,
                      (void*)&cnts, (void*)&btot, (void*)&bucketbase,
                      (void*)&staging, (void*)&csr, (void*)&rowstart,
                      (void*)&dinv, (void*)&tmp16, (void*)&pooled };
    hipError_t cerr = hipLaunchCooperativeKernel((void*)k_merged, dim3(MGRID), dim3(256),
                                                 kargs, 0, stream);
    if (cerr != hipSuccess) {
        (void)hipGetLastError();   // clear sticky error, use proven separate-kernel chain
        k_pre<<<PRE_BLKS, 256, 0, stream>>>(W1, W2, w1h, w1l, w2h, w2l, dstp, cnts, pooled);
        k_colscan<<<NBUCK, 256, 0, stream>>>(cnts, btot);
        k_gemmfill<<<GFB, 256, 0, stream>>>(x, w1h, w1l, tmp16, srcp, dstp, cnts, btot,
                                            bucketbase, staging);
        k_passB<<<NBUCK, 256, 0, stream>>>(staging, bucketbase, csr, rowstart, dinv, tmp16);
    }

    // fused: layer-1 aggregation (coefficient-free gather) + layer-2 GEMM
    k_agg1gemm<<<AGB, 256, 0, stream>>>(tmp16, csr, rowstart, dinv, b1, w2h, w2l, tmp2);

    // layer-2 aggregation + fused pooling (atomics into pooled)
    k_agg<<<AGB, 256, 0, stream>>>(tmp2, csr, rowstart, dinv, b2, batch, pooled);

    // slim pool-finish + fc + head
    k_poolhead<<<G, 128, 0, stream>>>(pooled, batch, Wfc, bfc, Wh, bh, out);
}

// Round 12
// 205.306 us; speedup vs baseline: 2.8771x; 2.8771x over previous
//
#include <hip/hip_runtime.h>
#include <math.h>

constexpr int N = 50000;   // nodes
constexpr int E = 800000;  // edges (without self-loops)
constexpr int F = 128;     // features / hidden
constexpr int G = 256;     // graphs
constexpr int T = 4;       // tasks

constexpr int BSH   = 5;                         // 32 nodes per bucket
constexpr int BNODES= 1 << BSH;
constexpr int NBUCK = (N + BNODES - 1) / BNODES; // 1563
constexpr int CHUNK = 4096;                      // edges per partition unit (196 units)
constexpr int NCHUNK= (E + CHUNK - 1) / CHUNK;   // 196
constexpr int SSH   = 13;                        // src-slice shift: 8192-node slices

constexpr int GB1 = (N + 63) / 64;               // 782 gemm tiles
constexpr int GFB = GB1 + NCHUNK;                // fused gemm+fillb grid (978)
constexpr int AGB = N / 16;                      // 3125 agg blocks (16 nodes/block)

// k_pre block-range layout: [wcastW1 64 | wcastW2 64 | zero pooled 128 | hist 196]
constexpr int MP_W2  = 64;
constexpr int MP_Z0  = 128;
constexpr int MP_H0  = 256;
constexpr int PRE_BLKS = MP_H0 + NCHUNK;         // 452

typedef __attribute__((ext_vector_type(8))) short short8;
typedef __attribute__((ext_vector_type(4))) float floatx4;

// bf16 <-> fp32 helpers (RNE on pack; values are finite)
__device__ inline float bf2f(unsigned short u) {
    union { unsigned int i; float f; } v;
    v.i = ((unsigned int)u) << 16;
    return v.f;
}
__device__ inline unsigned short f2bf(float f) {
    union { float f; unsigned int i; } v;
    v.f = f;
    unsigned int r = v.i + 0x7FFF + ((v.i >> 16) & 1);
    return (unsigned short)(r >> 16);
}
__device__ inline unsigned int pack2bf(float a, float b) {
    return (unsigned int)f2bf(a) | ((unsigned int)f2bf(b) << 16);
}

// pack W (fp32) -> MFMA-B-fragment order, hi/lo bf16 split
__device__ inline void wcast_one(const float* __restrict__ W,
                                 unsigned short* __restrict__ Whi,
                                 unsigned short* __restrict__ Wlo, int i) {
    if (i >= F * F) return;
    int k = i >> 7, n = i & 127;
    float w = W[i];
    unsigned short hi = f2bf(w);
    unsigned short lo = f2bf(w - bf2f(hi));
    int s = k >> 5, q = (k >> 3) & 3, j = k & 7;
    int idx = (((s * 128 + n) * 4 + q) * 8) + j;
    Whi[idx] = hi;
    Wlo[idx] = lo;
}

// ---------------- GEMM tile body (direct-reg A, no LDS) ----------------
__device__ __forceinline__ void gemm_tile(const float* __restrict__ x,
                                          const unsigned short* __restrict__ w1h,
                                          const unsigned short* __restrict__ w1l,
                                          unsigned short* __restrict__ tmp16,
                                          int tile, int t) {
    int wv = t >> 6;
    int lane = t & 63;
    int c16 = lane & 15;
    int q = lane >> 4;
    int arow = tile * 64 + wv * 16 + c16;

    short8 afr[4];
    if (arow < N) {
        const float4* xr = (const float4*)(x + (size_t)arow * 128);
#pragma unroll
        for (int s = 0; s < 4; ++s) {
            float4 v0 = xr[s * 8 + q * 2];
            float4 v1 = xr[s * 8 + q * 2 + 1];
            short8 a;
            a[0] = (short)f2bf(v0.x); a[1] = (short)f2bf(v0.y);
            a[2] = (short)f2bf(v0.z); a[3] = (short)f2bf(v0.w);
            a[4] = (short)f2bf(v1.x); a[5] = (short)f2bf(v1.y);
            a[6] = (short)f2bf(v1.z); a[7] = (short)f2bf(v1.w);
            afr[s] = a;
        }
    } else {
#pragma unroll
        for (int s = 0; s < 4; ++s) afr[s] = (short8){0,0,0,0,0,0,0,0};
    }

    floatx4 acc[8];
#pragma unroll
    for (int nt = 0; nt < 8; ++nt) acc[nt] = (floatx4){0.f, 0.f, 0.f, 0.f};

    const short8* WH = (const short8*)w1h;
    const short8* WL = (const short8*)w1l;
#pragma unroll
    for (int s = 0; s < 4; ++s) {
        int wb = s * 512 + c16 * 4 + q;
#pragma unroll
        for (int nt = 0; nt < 8; ++nt) {
            acc[nt] = __builtin_amdgcn_mfma_f32_16x16x32_bf16(afr[s], WH[wb + nt * 64], acc[nt], 0, 0, 0);
            acc[nt] = __builtin_amdgcn_mfma_f32_16x16x32_bf16(afr[s], WL[wb + nt * 64], acc[nt], 0, 0, 0);
        }
    }

    int rbase = tile * 64 + wv * 16 + q * 4;
#pragma unroll
    for (int r = 0; r < 4; ++r) {
        int row = rbase + r;
        if (row < N) {
#pragma unroll
            for (int nt = 0; nt < 8; ++nt)
                tmp16[row * 128 + nt * 16 + c16] = f2bf(acc[nt][r]);
        }
    }
}

// ------ fused preamble: wcast(W1/W2) + zero pooled + per-chunk LDS bucket histogram ------
__global__ __launch_bounds__(256) void k_pre(const float* __restrict__ W1, const float* __restrict__ W2,
                                             unsigned short* __restrict__ w1h, unsigned short* __restrict__ w1l,
                                             unsigned short* __restrict__ w2h, unsigned short* __restrict__ w2l,
                                             const int* __restrict__ dst, int* __restrict__ cnts,
                                             float* __restrict__ pooled) {
    __shared__ int h[NBUCK];
    int b = blockIdx.x, t = threadIdx.x;
    if (b < MP_W2) {
        wcast_one(W1, w1h, w1l, b * 256 + t);
    } else if (b < MP_Z0) {
        wcast_one(W2, w2h, w2l, (b - MP_W2) * 256 + t);
    } else if (b < MP_H0) {
        pooled[(b - MP_Z0) * 256 + t] = 0.f;       // G*F = 32768 exactly
    } else {
        int chunk = b - MP_H0;
        for (int i = t; i < NBUCK; i += 256) h[i] = 0;
        __syncthreads();
        int base = chunk * CHUNK;
        for (int i = t; i < CHUNK; i += 256) {
            int e = base + i;
            if (e < E) atomicAdd(&h[dst[e] >> BSH], 1);   // LDS atomic
        }
        __syncthreads();
        for (int i = t; i < NBUCK; i += 256) cnts[chunk * NBUCK + i] = h[i];
    }
}

// ---- parallel colscan: one block per bucket, in-block scan over NCHUNK=196 values ----
__global__ __launch_bounds__(256) void k_colscan(int* __restrict__ cnts, int* __restrict__ btot) {
    __shared__ int part[256];
    int j = blockIdx.x, t = threadIdx.x;
    int k0 = 2 * t, k1 = 2 * t + 1;
    int v0 = (k0 < NCHUNK) ? cnts[k0 * NBUCK + j] : 0;
    int v1 = (k1 < NCHUNK) ? cnts[k1 * NBUCK + j] : 0;
    int s = v0 + v1;
    part[t] = s;
    __syncthreads();
    for (int off = 1; off < 256; off <<= 1) {
        int u = (t >= off) ? part[t - off] : 0;
        __syncthreads();
        part[t] += u;
        __syncthreads();
    }
    int excl = part[t] - s;
    if (k0 < NCHUNK) cnts[k0 * NBUCK + j] = excl;
    if (k1 < NCHUNK) cnts[k1 * NBUCK + j] = excl + v0;
    if (t == 255) btot[j] = part[255];
}

// ------- fused: layer-1 GEMM (blocks < GB1, direct-reg A) + fillb (blocks >= GB1) -------
__global__ __launch_bounds__(256) void k_gemmfill(const float* __restrict__ x,
                                                  const unsigned short* __restrict__ w1h,
                                                  const unsigned short* __restrict__ w1l,
                                                  unsigned short* __restrict__ tmp16,
                                                  const int* __restrict__ src,
                                                  const int* __restrict__ dst,
                                                  const int* __restrict__ cnts,
                                                  const int* __restrict__ btot,
                                                  int* __restrict__ bucketbase,
                                                  unsigned int* __restrict__ staging) {
    __shared__ __align__(16) char smem[13536];
    int b = blockIdx.x, t = threadIdx.x;
    if (b < GB1) {
        gemm_tile(x, w1h, w1l, tmp16, b, t);
        return;
    }
    // ---- fillb: deterministic partition into bucket-contiguous staging ----
    int* bb   = (int*)smem;                    // NBUCK+1 = 1564 (6256 B)
    int* part = (int*)(smem + 6256);           // 256 (1024 B)
    int* lofs = (int*)(smem + 7280);           // NBUCK (6252 B) -> 13532 total
    int chunk = b - GB1;

    // redundant per-block exclusive scan of btot -> bb
    constexpr int CH = (NBUCK + 255) / 256;    // 7
    int beg = t * CH;
    int end = (beg + CH < NBUCK) ? beg + CH : NBUCK;
    int tot[CH];
    int s = 0;
    for (int i = beg; i < end; ++i) {
        tot[i - beg] = btot[i];
        s += btot[i];
    }
    part[t] = s;
    __syncthreads();
    for (int off = 1; off < 256; off <<= 1) {
        int u = (t >= off) ? part[t - off] : 0;
        __syncthreads();
        part[t] += u;
        __syncthreads();
    }
    int run = (t == 0) ? 0 : part[t - 1];
    for (int i = beg; i < end; ++i) {
        bb[i] = run;
        run += tot[i - beg];
    }
    if (t == 255) bb[NBUCK] = part[255];       // == E
    __syncthreads();
    if (chunk == 0)
        for (int i = t; i <= NBUCK; i += 256) bucketbase[i] = bb[i];

    for (int i = t; i < NBUCK; i += 256)
        lofs[i] = bb[i] + cnts[chunk * NBUCK + i];
    __syncthreads();

    int base = chunk * CHUNK;
    for (int i = t; i < CHUNK; i += 256) {
        int e = base + i;
        if (e < E) {
            int d = dst[e];
            int pos = atomicAdd(&lofs[d >> BSH], 1);   // LDS atomic
            staging[pos] = (unsigned int)src[e] | ((unsigned int)(d & (BNODES - 1)) << 16);
        }
    }
}

// ---- pass B: per-bucket counting sort + dinv + in-place pre-scale of tmp16 rows ----
__global__ __launch_bounds__(256) void k_passB(const unsigned int* __restrict__ staging,
                                               const int* __restrict__ bucketbase,
                                               int* __restrict__ csr,
                                               int* __restrict__ rowstart,
                                               float* __restrict__ dinv,
                                               unsigned short* __restrict__ tmp16) {
    __shared__ unsigned int ent[1024];        // mean 512, 11-sigma safe
    __shared__ int h[BNODES * 8], off_a[BNODES * 8];   // (node, slice) bins
    __shared__ int nodebase[BNODES], ndeg[BNODES];
    __shared__ float sdinv[BNODES];
    int b = blockIdx.x, t = threadIdx.x;
    int jb = bucketbase[b], je = bucketbase[b + 1];
    int M = je - jb;
    if (M > 1024) M = 1024;
    if (t < BNODES * 8) h[t] = 0;
    __syncthreads();

    for (int i = t; i < M; i += 256) {
        unsigned int en = staging[jb + i];
        ent[i] = en;
        int key = (((en >> 16) & (BNODES - 1)) << 3) | ((en & 0xFFFFu) >> SSH);
        atomicAdd(&h[key], 1);
    }
    __syncthreads();

    if (t < BNODES) {
        int s = 0;
#pragma unroll
        for (int c = 0; c < 8; ++c) s += h[t * 8 + c];
        ndeg[t] = s;
    }
    __syncthreads();
    if (t == 0) {
        int run = jb;
        for (int k = 0; k < BNODES; ++k) {
            nodebase[k] = run;
            run += ndeg[k];
        }
    }
    __syncthreads();
    if (t < BNODES) {
        int run = nodebase[t];
#pragma unroll
        for (int c = 0; c < 8; ++c) {
            off_a[t * 8 + c] = run;
            run += h[t * 8 + c];
        }
        float dv = rsqrtf((float)(ndeg[t] + 1));     // +1 self-loop
        sdinv[t] = dv;
        int node = b * BNODES + t;
        if (node < N) {
            rowstart[node] = nodebase[t];
            dinv[node] = dv;
        }
    }
    if (b == 0 && t == 0) rowstart[N] = E;
    __syncthreads();

    for (int i = t; i < M; i += 256) {
        unsigned int en = ent[i];
        int key = (((en >> 16) & (BNODES - 1)) << 3) | ((en & 0xFFFFu) >> SSH);
        int loc = atomicAdd(&off_a[key], 1);
        csr[loc] = (int)(en & 0xFFFFu);
    }

    // ---- in-place scale: tmp16[row] *= dinv[row] for this bucket's 32 rows ----
    uint4* t4 = (uint4*)tmp16;
    for (int i = t; i < BNODES * 16; i += 256) {     // 512 uint4, 2 per thread
        int rl = i >> 4, qi = i & 15;
        int node = b * BNODES + rl;
        if (node < N) {
            float dv = sdinv[rl];
            uint4 u = t4[node * 16 + qi];
            uint4 o;
            o.x = pack2bf(bf2f((unsigned short)(u.x & 0xFFFFu)) * dv, bf2f((unsigned short)(u.x >> 16)) * dv);
            o.y = pack2bf(bf2f((unsigned short)(u.y & 0xFFFFu)) * dv, bf2f((unsigned short)(u.y >> 16)) * dv);
            o.z = pack2bf(bf2f((unsigned short)(u.z & 0xFFFFu)) * dv, bf2f((unsigned short)(u.z >> 16)) * dv);
            o.w = pack2bf(bf2f((unsigned short)(u.w & 0xFFFFu)) * dv, bf2f((unsigned short)(u.w >> 16)) * dv);
            t4[node * 16 + qi] = o;
        }
    }
}

// 8 bf16 (uint4) add into 8 fp32 accumulators (coefficient-free hot path)
__device__ inline void add8(const uint4& u, float* acc) {
    union { unsigned int i; float f; } a;
    a.i = u.x << 16;          acc[0] += a.f;
    a.i = u.x & 0xFFFF0000u;  acc[1] += a.f;
    a.i = u.y << 16;          acc[2] += a.f;
    a.i = u.y & 0xFFFF0000u;  acc[3] += a.f;
    a.i = u.z << 16;          acc[4] += a.f;
    a.i = u.z & 0xFFFF0000u;  acc[5] += a.f;
    a.i = u.w << 16;          acc[6] += a.f;
    a.i = u.w & 0xFFFF0000u;  acc[7] += a.f;
}

// 8 bf16 (uint4) fma into 8 fp32 accumulators (masked tail + pooling)
__device__ inline void fma8(const uint4& u, float c, float* acc) {
    union { unsigned int i; float f; } a;
    a.i = u.x << 16;          acc[0] = fmaf(a.f, c, acc[0]);
    a.i = u.x & 0xFFFF0000u;  acc[1] = fmaf(a.f, c, acc[1]);
    a.i = u.y << 16;          acc[2] = fmaf(a.f, c, acc[2]);
    a.i = u.y & 0xFFFF0000u;  acc[3] = fmaf(a.f, c, acc[3]);
    a.i = u.z << 16;          acc[4] = fmaf(a.f, c, acc[4]);
    a.i = u.z & 0xFFFF0000u;  acc[5] = fmaf(a.f, c, acc[5]);
    a.i = u.w << 16;          acc[6] = fmaf(a.f, c, acc[6]);
    a.i = u.w & 0xFFFF0000u;  acc[7] = fmaf(a.f, c, acc[7]);
}

// agg inner loop (round-5 proven form): 8-deep full chunks with next-chunk csr
// prefetch; one masked tail. r6 (16-deep ILP) and r7 (node-split TLP) both
// regressed — the gather is at the memory-system's random-access service limit.
__device__ __forceinline__ void agg_loop(const uint4* __restrict__ t8l,  // t8 + lane
                                         const int* __restrict__ csr,
                                         int jb, int je, float* acc) {
    int n8 = (je - jb) >> 3;
    int j = jb;
    if (n8 > 0) {
        int e[8];
#pragma unroll
        for (int k = 0; k < 8; ++k) e[k] = csr[j + k];
        for (int c = 0; c < n8; ++c) {
            uint4 u[8];
#pragma unroll
            for (int k = 0; k < 8; ++k) u[k] = t8l[e[k] * 16];
            j += 8;
            if (c + 1 < n8) {
#pragma unroll
                for (int k = 0; k < 8; ++k) e[k] = csr[j + k];   // prefetch next chunk's indices
            }
#pragma unroll
            for (int k = 0; k < 8; ++k) add8(u[k], acc);
        }
    }
    if (j < je) {                       // masked tail (1..7 edges)
        int e[8];
        float msk[8];
#pragma unroll
        for (int k = 0; k < 8; ++k) {
            int idx = j + k;
            e[k] = csr[idx < je ? idx : je - 1];
            msk[k] = (idx < je) ? 1.0f : 0.0f;
        }
        uint4 u[8];
#pragma unroll
        for (int k = 0; k < 8; ++k) u[k] = t8l[e[k] * 16];
#pragma unroll
        for (int k = 0; k < 8; ++k) fma8(u[k], msk[k], acc);
    }
}

// ---------------- fused layer-1 agg + layer-2 GEMM (16 nodes/block) ----------------
__global__ __launch_bounds__(256) void k_agg1gemm(const unsigned short* __restrict__ tmp16,
                                                  const int* __restrict__ csr,
                                                  const int* __restrict__ rowstart,
                                                  const float* __restrict__ dinv,
                                                  const float* __restrict__ bias,
                                                  const unsigned short* __restrict__ w2h,
                                                  const unsigned short* __restrict__ w2l,
                                                  unsigned short* __restrict__ tmp2) {
    __shared__ __align__(16) unsigned short Albs[16 * 136];
    int tid = threadIdx.x;
    int row0 = blockIdx.x * 16;

    // ---- phase A: aggregation (h1 = relu(dinv_d * sum(tmp16[s]) + b1); tmp16 pre-scaled) ----
    {
        int node = row0 + (tid >> 4);
        int lane = tid & 15;
        const uint4* t8l = (const uint4*)tmp16 + lane;
        float acc[8] = {0.f, 0.f, 0.f, 0.f, 0.f, 0.f, 0.f, 0.f};
        add8(t8l[node * 16], acc);                       // self-loop term
        agg_loop(t8l, csr, rowstart[node], rowstart[node + 1], acc);

        float di = dinv[node];
        const float4* b4 = (const float4*)bias;
        float4 ba = b4[lane * 2], bb = b4[lane * 2 + 1];
        uint4 o;
        o.x = pack2bf(fmaxf(fmaf(acc[0], di, ba.x), 0.f), fmaxf(fmaf(acc[1], di, ba.y), 0.f));
        o.y = pack2bf(fmaxf(fmaf(acc[2], di, ba.z), 0.f), fmaxf(fmaf(acc[3], di, ba.w), 0.f));
        o.z = pack2bf(fmaxf(fmaf(acc[4], di, bb.x), 0.f), fmaxf(fmaf(acc[5], di, bb.y), 0.f));
        o.w = pack2bf(fmaxf(fmaf(acc[6], di, bb.z), 0.f), fmaxf(fmaf(acc[7], di, bb.w), 0.f));
        *(uint4*)&Albs[(tid >> 4) * 136 + lane * 8] = o;
    }
    __syncthreads();

    // ---- phase B: 16-row MFMA gemm, 4 waves x 2 n-tiles; output pre-scaled by dinv ----
    int wv = tid >> 6;
    int lane = tid & 63;
    int c16 = lane & 15;
    int q = lane >> 4;

    floatx4 acc[2];
    acc[0] = (floatx4){0.f, 0.f, 0.f, 0.f};
    acc[1] = (floatx4){0.f, 0.f, 0.f, 0.f};

    const short8* WH = (const short8*)w2h;
    const short8* WL = (const short8*)w2l;
#pragma unroll
    for (int s = 0; s < 4; ++s) {
        short8 a = *(const short8*)&Albs[c16 * 136 + s * 32 + q * 8];
        int wb = s * 512 + c16 * 4 + q;
#pragma unroll
        for (int i = 0; i < 2; ++i) {
            int nt = wv * 2 + i;
            acc[i] = __builtin_amdgcn_mfma_f32_16x16x32_bf16(a, WH[wb + nt * 64], acc[i], 0, 0, 0);
            acc[i] = __builtin_amdgcn_mfma_f32_16x16x32_bf16(a, WL[wb + nt * 64], acc[i], 0, 0, 0);
        }
    }

    int rbase = row0 + q * 4;
#pragma unroll
    for (int r = 0; r < 4; ++r) {
        int row = rbase + r;
        float dv = dinv[row];
#pragma unroll
        for (int i = 0; i < 2; ++i) {
            int nt = wv * 2 + i;
            tmp2[row * 128 + nt * 16 + c16] = f2bf(acc[i][r] * dv);
        }
    }
}

// ------- layer-2 aggregation + fused pooling (batch sorted -> LDS run-reduce + atomics) -------
__global__ __launch_bounds__(256) void k_agg(const unsigned short* __restrict__ tmp16,
                                             const int* __restrict__ csr,
                                             const int* __restrict__ rowstart,
                                             const float* __restrict__ dinv,
                                             const float* __restrict__ bias,
                                             const int* __restrict__ batch,
                                             float* __restrict__ pooled) {
    __shared__ float red[16][128];
    __shared__ int gid[16];
    int tid = threadIdx.x;
    int node0 = blockIdx.x * 16;              // AGB*16 == N exactly
    int ns = tid >> 4, lane = tid & 15;
    int node = node0 + ns;
    const uint4* t8l = (const uint4*)tmp16 + lane;
    float acc[8] = {0.f, 0.f, 0.f, 0.f, 0.f, 0.f, 0.f, 0.f};
    add8(t8l[node * 16], acc);
    agg_loop(t8l, csr, rowstart[node], rowstart[node + 1], acc);

    float di = dinv[node];
    const float4* b4 = (const float4*)bias;
    float4 ba = b4[lane * 2], bb = b4[lane * 2 + 1];
    red[ns][lane * 8 + 0] = fmaxf(fmaf(acc[0], di, ba.x), 0.f);
    red[ns][lane * 8 + 1] = fmaxf(fmaf(acc[1], di, ba.y), 0.f);
    red[ns][lane * 8 + 2] = fmaxf(fmaf(acc[2], di, ba.z), 0.f);
    red[ns][lane * 8 + 3] = fmaxf(fmaf(acc[3], di, ba.w), 0.f);
    red[ns][lane * 8 + 4] = fmaxf(fmaf(acc[4], di, bb.x), 0.f);
    red[ns][lane * 8 + 5] = fmaxf(fmaf(acc[5], di, bb.y), 0.f);
    red[ns][lane * 8 + 6] = fmaxf(fmaf(acc[6], di, bb.z), 0.f);
    red[ns][lane * 8 + 7] = fmaxf(fmaf(acc[7], di, bb.w), 0.f);
    if (tid < 16) gid[tid] = batch[node0 + tid];
    __syncthreads();

    if (tid < 128) {
        int f = tid;
        float run = 0.f;
        int g = gid[0];
        for (int r = 0; r < 16; ++r) {
            if (gid[r] != g) {
                atomicAdd(&pooled[g * 128 + f], run);
                run = 0.f;
                g = gid[r];
            }
            run += red[r][f];
        }
        atomicAdd(&pooled[g * 128 + f], run);
    }
}

// ---------------- slim pool-finish + fc + head: reads pooled sums only ----------------
__global__ __launch_bounds__(128) void k_poolhead(const float* __restrict__ pooled,
                                                  const int* __restrict__ batch,
                                                  const float* __restrict__ Wfc,
                                                  const float* __restrict__ bfc,
                                                  const float* __restrict__ Wh,
                                                  const float* __restrict__ bh,
                                                  float* __restrict__ out) {
    __shared__ float p[128];
    __shared__ float zs[128];
    int g = blockIdx.x, t = threadIdx.x;

    int lo = 0, hi = N;                       // lower_bound(g)
    while (lo < hi) { int m = (lo + hi) >> 1; if (batch[m] < g) lo = m + 1; else hi = m; }
    int lo1 = lo, hi1 = N;                    // lower_bound(g+1)
    while (lo1 < hi1) { int m = (lo1 + hi1) >> 1; if (batch[m] < g + 1) lo1 = m + 1; else hi1 = m; }
    int cnt = lo1 - lo;
    float inv = 1.0f / (float)((cnt > 1) ? cnt : 1);

    p[t] = pooled[g * 128 + t] * inv;
    __syncthreads();

    float a = bfc[t];
    for (int k = 0; k < F; ++k) a = fmaf(p[k], Wfc[k * F + t], a);
    zs[t] = fmaxf(a, 0.f);
    __syncthreads();

    if (t < T * 2) {
        int task = t >> 1, c = t & 1;
        float a2 = bh[task * 2 + c];
        const float* wr = &Wh[task * F * 2 + c];
        for (int h = 0; h < F; ++h) a2 = fmaf(zs[h], wr[h * 2], a2);
        out[task * (G * 2) + g * 2 + c] = a2;
    }
}

extern "C" void kernel_launch(void* const* d_in, const int* in_sizes, int n_in,
                              void* d_out, int out_size, void* d_ws, size_t ws_size,
                              hipStream_t stream) {
    const float* x    = (const float*)d_in[0];
    const int*   ei   = (const int*)d_in[1];      // [2,E]: row0=src, row1=dst
    const int*   batch= (const int*)d_in[2];
    const float* W1   = (const float*)d_in[3];
    const float* b1   = (const float*)d_in[4];
    const float* W2   = (const float*)d_in[5];
    const float* b2   = (const float*)d_in[6];
    const float* Wfc  = (const float*)d_in[7];
    const float* bfc  = (const float*)d_in[8];
    const float* Wh   = (const float*)d_in[9];
    const float* bh   = (const float*)d_in[10];
    float* out = (float*)d_out;

    const int* srcp = ei;
    const int* dstp = ei + E;

    char* w = (char*)d_ws;
    auto alloc = [&](size_t bytes) {
        char* p = w;
        w += (bytes + 255) & ~(size_t)255;
        return p;
    };
    unsigned short* tmp16 = (unsigned short*)alloc((size_t)N * F * 2);
    unsigned short* tmp2  = (unsigned short*)alloc((size_t)N * F * 2);
    int*   csr      = (int*)  alloc((size_t)E * 4);
    unsigned int* staging = (unsigned int*)alloc((size_t)E * 4);
    int*   cnts     = (int*)  alloc((size_t)NCHUNK * NBUCK * 4);
    int*   btot     = (int*)  alloc((size_t)NBUCK * 4);
    int*   bucketbase=(int*)  alloc((size_t)(NBUCK + 1) * 4);
    int*   rowstart = (int*)  alloc((size_t)(N + 1) * 4);
    float* dinv     = (float*)alloc((size_t)N * 4);
    float* pooled   = (float*)alloc((size_t)G * F * 4);
    unsigned short* w1h = (unsigned short*)alloc((size_t)F * F * 2);
    unsigned short* w1l = (unsigned short*)alloc((size_t)F * F * 2);
    unsigned short* w2h = (unsigned short*)alloc((size_t)F * F * 2);
    unsigned short* w2l = (unsigned short*)alloc((size_t)F * F * 2);

    // fused preamble: wcast W1/W2 + zero pooled + per-chunk LDS bucket histogram
    k_pre<<<PRE_BLKS, 256, 0, stream>>>(W1, W2, w1h, w1l, w2h, w2l, dstp, cnts, pooled);

    // parallel colscan (tiny): cnts -> within-bucket offsets + btot
    k_colscan<<<NBUCK, 256, 0, stream>>>(cnts, btot);

    // fused: layer-1 GEMM (direct-reg A, no LDS) + fillb partition (hidden under GEMM)
    k_gemmfill<<<GFB, 256, 0, stream>>>(x, w1h, w1l, tmp16, srcp, dstp, cnts, btot,
                                        bucketbase, staging);

    // passB: counting sort + dinv + in-place pre-scale of tmp16
    k_passB<<<NBUCK, 256, 0, stream>>>(staging, bucketbase, csr, rowstart, dinv, tmp16);

    // fused: layer-1 aggregation (coefficient-free gather) + layer-2 GEMM
    k_agg1gemm<<<AGB, 256, 0, stream>>>(tmp16, csr, rowstart, dinv, b1, w2h, w2l, tmp2);

    // layer-2 aggregation + fused pooling (atomics into pooled)
    k_agg<<<AGB, 256, 0, stream>>>(tmp2, csr, rowstart, dinv, b2, batch, pooled);

    // slim pool-finish + fc + head
    k_poolhead<<<G, 128, 0, stream>>>(pooled, batch, Wfc, bfc, Wh, bh, out);
}